// Round 7
// baseline (406.503 us; speedup 1.0000x reference)
//
#include <hip/hip_runtime.h>
#include <hip/hip_bf16.h>
#include <math.h>

// N=50000, E=500000, SED=128, HID=64, H=2, F_node=128
// Round 7: single-pass agg with inline exp (no ex-array kernels), software-
// prefetched gather rounds + v_pk_fma float2 accumulation; de-duplicated
// edge head; single-block scan. MFMA node GEMMs unchanged.

typedef short short8 __attribute__((ext_vector_type(8)));
typedef float floatx4 __attribute__((ext_vector_type(4)));
typedef float v2f __attribute__((ext_vector_type(2)));
typedef unsigned uint2v __attribute__((ext_vector_type(2)));

__device__ __forceinline__ float wave_allreduce_sum(float v) {
    #pragma unroll
    for (int off = 1; off < 64; off <<= 1) v += __shfl_xor(v, off, 64);
    return v;
}
__device__ __forceinline__ float bf16lo(unsigned u) {
    unsigned x = u << 16; return __builtin_bit_cast(float, x);
}
__device__ __forceinline__ float bf16hi(unsigned u) {
    unsigned x = u & 0xFFFF0000u; return __builtin_bit_cast(float, x);
}
__device__ __forceinline__ v2f bfpair(unsigned v) {
    uint2v t; t.x = v << 16; t.y = v & 0xFFFF0000u;
    return __builtin_bit_cast(v2f, t);
}
__device__ __forceinline__ unsigned short bfbits(float f) {
    return __builtin_bit_cast(unsigned short, __float2bfloat16(f));
}
__device__ __forceinline__ unsigned packbf(float a, float b) {
    return ((unsigned)bfbits(b) << 16) | (unsigned)bfbits(a);
}
__device__ __forceinline__ float lrelu(float v) { return v > 0.f ? v : 0.2f * v; }

// ---- prep: sent/c1; bf16 B-fragment tables for W1, W2, fc2(split) ----
__global__ void prep_kernel(const float* __restrict__ cls, const float* __restrict__ fc0_w,
                            const float* __restrict__ fc0_b, const float* __restrict__ W1,
                            const float* __restrict__ W2, const float* __restrict__ fc2_w,
                            float* __restrict__ c1,
                            __hip_bfloat16* __restrict__ w1frag,
                            __hip_bfloat16* __restrict__ w2frag,
                            __hip_bfloat16* __restrict__ fc2frag) {
    int tid = threadIdx.x;
    if (blockIdx.x == 0) {
        __shared__ float s_sent[128];
        if (tid < 128) {
            float acc = fc0_b[tid];
            const float* row = fc0_w + (size_t)tid * 768;
            for (int k = 0; k < 768; ++k) acc += row[k] * cls[k];
            s_sent[tid] = acc;
        }
        __syncthreads();
        if (tid < 128) {
            float acc = 0.f;
            for (int k = 0; k < 128; ++k) acc += s_sent[k] * W1[(128 + k) * 128 + tid];
            c1[tid] = acc;
        }
    }
    int gstride = gridDim.x * blockDim.x;
    int g = blockIdx.x * blockDim.x + tid;
    for (int i = g; i < 16384; i += gstride) {
        int j = i & 7, l = (i >> 3) & 63, nt = (i >> 9) & 7, kt = (i >> 12) & 3;
        int k = kt * 32 + (l >> 4) * 8 + j;
        int n = nt * 16 + (l & 15);
        w1frag[i] = __float2bfloat16(W1[k * 128 + n]);
    }
    for (int i = g; i < 32768; i += gstride) {
        int j = i & 7, l = (i >> 3) & 63, nt = (i >> 9) & 15, kt = (i >> 13) & 3;
        int k = kt * 32 + (l >> 4) * 8 + j;
        int n = nt * 16 + (l & 15);
        w2frag[i] = __float2bfloat16(W2[k * 256 + n]);
    }
    for (int i = g; i < 32768; i += gstride) {
        int j = i & 7, l = (i >> 3) & 63, nt = (i >> 9) & 15, kt = (i >> 13) & 3;
        int k = kt * 32 + (l >> 4) * 8 + j;
        int n = nt * 16 + (l & 15);
        float v = (n < 128) ? fc2_w[n * 256 + k] : fc2_w[(n - 128) * 256 + 128 + k];
        fc2frag[i] = __float2bfloat16(v);
    }
}

// ---- CSR build ----
__global__ void count_kernel(const int* __restrict__ dst, int* __restrict__ counts, int E) {
    int e = blockIdx.x * blockDim.x + threadIdx.x;
    if (e < E) atomicAdd(&counts[dst[e]], 1);
}

__global__ void __launch_bounds__(1024) scan_kernel(const int* __restrict__ counts,
                                                    int* __restrict__ row, int* __restrict__ woff,
                                                    int N, int E) {
    int tid = threadIdx.x, lane = tid & 63, wv = tid >> 6;
    __shared__ int wsum[16];
    __shared__ int carry;
    if (tid == 0) carry = 0;
    __syncthreads();
    for (int base = 0; base < N; base += 1024) {
        int v = (base + tid < N) ? counts[base + tid] : 0;
        int x = v;
        #pragma unroll
        for (int off = 1; off < 64; off <<= 1) {
            int t = __shfl_up(x, off, 64);
            if (lane >= off) x += t;
        }
        if (lane == 63) wsum[wv] = x;
        __syncthreads();
        if (wv == 0 && lane < 16) {
            int y = wsum[lane];
            #pragma unroll
            for (int off = 1; off < 16; off <<= 1) {
                int t = __shfl_up(y, off, 64);
                if (lane >= off) y += t;
            }
            wsum[lane] = y;
        }
        __syncthreads();
        int wexcl = (wv == 0) ? 0 : wsum[wv - 1];
        int excl = carry + wexcl + x - v;
        if (base + tid < N) { row[base + tid] = excl; woff[base + tid] = excl; }
        __syncthreads();
        if (tid == 0) carry += wsum[15];
        __syncthreads();
    }
    if (tid == 0) row[N] = E;
}

__global__ void scatter_kernel(const int* __restrict__ src, const int* __restrict__ dst,
                               int* __restrict__ woff, int* __restrict__ srcs, int E) {
    int e = blockIdx.x * blockDim.x + threadIdx.x;
    if (e < E) {
        int pos = atomicAdd(&woff[dst[e]], 1);
        srcs[pos] = src[e];
    }
}

// ---- gemm1 MFMA (cvt fused): h1bf = bf16(x) @ W1frag + c1 ; logits ----
__global__ void __launch_bounds__(256) gemm1_mfma_kernel(
        const float* __restrict__ x, const __hip_bfloat16* __restrict__ wfrag,
        const float* __restrict__ c1, const float* __restrict__ att_s, const float* __restrict__ att_d,
        __hip_bfloat16* __restrict__ h1bf, float* __restrict__ a_src, float* __restrict__ a_dst, int N) {
    int lane = threadIdx.x & 63, wv = threadIdx.x >> 6;
    int lo = lane & 15, quad = lane >> 4;
    int rowbase = (blockIdx.x * 4 + wv) * 16;
    if (rowbase >= N) return;
    int arow = rowbase + lo; if (arow >= N) arow = N - 1;
    const float* ap = x + (size_t)arow * 128 + quad * 8;
    floatx4 acc[8];
    #pragma unroll
    for (int nt = 0; nt < 8; ++nt) acc[nt] = (floatx4){0.f, 0.f, 0.f, 0.f};
    const short8* bf = (const short8*)wfrag;
    #pragma unroll
    for (int kt = 0; kt < 4; ++kt) {
        float4 fa = *(const float4*)(ap + kt * 32);
        float4 fb = *(const float4*)(ap + kt * 32 + 4);
        short8 a;
        a[0] = (short)bfbits(fa.x); a[1] = (short)bfbits(fa.y);
        a[2] = (short)bfbits(fa.z); a[3] = (short)bfbits(fa.w);
        a[4] = (short)bfbits(fb.x); a[5] = (short)bfbits(fb.y);
        a[6] = (short)bfbits(fb.z); a[7] = (short)bfbits(fb.w);
        #pragma unroll
        for (int nt = 0; nt < 8; ++nt)
            acc[nt] = __builtin_amdgcn_mfma_f32_16x16x32_bf16(a, bf[(kt * 8 + nt) * 64 + lane], acc[nt], 0, 0, 0);
    }
    float ps0[4] = {0,0,0,0}, ps1[4] = {0,0,0,0}, pd0[4] = {0,0,0,0}, pd1[4] = {0,0,0,0};
    #pragma unroll
    for (int nt = 0; nt < 8; ++nt) {
        int ch = nt * 16 + lo;
        float cv = c1[ch], as_v = att_s[ch], ad_v = att_d[ch];
        #pragma unroll
        for (int r = 0; r < 4; ++r) {
            int row = rowbase + quad * 4 + r;
            float val = acc[nt][r] + cv;
            if (row < N) ((unsigned short*)h1bf)[(size_t)row * 128 + ch] = bfbits(val);
            if (nt < 4) { ps0[r] += val * as_v; pd0[r] += val * ad_v; }
            else        { ps1[r] += val * as_v; pd1[r] += val * ad_v; }
        }
    }
    #pragma unroll
    for (int r = 0; r < 4; ++r) {
        int row = rowbase + quad * 4 + r;
        float v0 = ps0[r], v1 = ps1[r], v2 = pd0[r], v3 = pd1[r];
        #pragma unroll
        for (int off = 1; off < 16; off <<= 1) {
            v0 += __shfl_xor(v0, off, 64); v1 += __shfl_xor(v1, off, 64);
            v2 += __shfl_xor(v2, off, 64); v3 += __shfl_xor(v3, off, 64);
        }
        if (lo == 0 && row < N) {
            a_src[row * 2 + 0] = v0; a_src[row * 2 + 1] = v1;
            a_dst[row * 2 + 0] = v2; a_dst[row * 2 + 1] = v3;
        }
    }
}

// ---- agg1: wave/dst, single pass, inline exp, prefetched rounds; ELU -> hmid bf16 ----
__global__ void __launch_bounds__(256) agg1_csr_kernel(
        const int* __restrict__ row, const int* __restrict__ srcs,
        const float* __restrict__ a_src, const float* __restrict__ a_dst,
        const unsigned* __restrict__ h1u, const float* __restrict__ bias1,
        unsigned* __restrict__ hmid_u, int N) {
    int d = blockIdx.x * 4 + (threadIdx.x >> 6);
    if (d >= N) return;
    int lane = threadIdx.x & 63;
    int beg = row[d], end = row[d + 1];
    int g = lane >> 4, q = lane & 15;
    float2 adp = ((const float2*)a_dst)[d];
    float den0 = 0.f, den1 = 0.f;
    v2f facc2[4];
    #pragma unroll
    for (int m = 0; m < 4; ++m) facc2[m] = (v2f){0.f, 0.f};
    for (int b = beg; b < end; b += 64) {
        int i = b + lane;
        int s = 0; float e0 = 0.f, e1 = 0.f;
        if (i < end) {
            s = srcs[i];
            float2 as = ((const float2*)a_src)[s];
            e0 = __expf(lrelu(as.x + adp.x));
            e1 = __expf(lrelu(as.y + adp.y));
            den0 += e0; den1 += e1;
        }
        int cnt = min(64, end - b);
        int rounds = (cnt + 3) >> 2;
        // prefetch round 0
        float w0 = __shfl(e0, g, 64);
        float w1 = __shfl(e1, g, 64);
        int   sj = __shfl(s,  g, 64);
        float wgt = (q < 8) ? w0 : w1;
        uint4 u = ((const uint4*)(h1u + (size_t)sj * 64))[q];
        for (int j = 0; j < rounds; ++j) {
            int sl2 = 4 * j + 4 + g; sl2 = sl2 > 63 ? 63 : sl2;
            float w0n = __shfl(e0, sl2, 64);
            float w1n = __shfl(e1, sl2, 64);
            int   sjn = __shfl(s,  sl2, 64);
            uint4 un = ((const uint4*)(h1u + (size_t)sjn * 64))[q];
            float wgtn = (q < 8) ? w0n : w1n;
            facc2[0] += bfpair(u.x) * wgt;
            facc2[1] += bfpair(u.y) * wgt;
            facc2[2] += bfpair(u.z) * wgt;
            facc2[3] += bfpair(u.w) * wgt;
            u = un; wgt = wgtn;
        }
    }
    den0 = wave_allreduce_sum(den0);
    den1 = wave_allreduce_sum(den1);
    #pragma unroll
    for (int m = 0; m < 4; ++m) {
        facc2[m].x += __shfl_xor(facc2[m].x, 16, 64);
        facc2[m].y += __shfl_xor(facc2[m].y, 16, 64);
        facc2[m].x += __shfl_xor(facc2[m].x, 32, 64);
        facc2[m].y += __shfl_xor(facc2[m].y, 32, 64);
    }
    if (lane < 16) {
        float inv = (lane < 8) ? 1.f / (den0 + 1e-16f) : 1.f / (den1 + 1e-16f);
        int c0 = 8 * lane;
        float v[8];
        #pragma unroll
        for (int m = 0; m < 4; ++m) {
            float va = facc2[m].x * inv + bias1[c0 + 2 * m];
            float vb = facc2[m].y * inv + bias1[c0 + 2 * m + 1];
            v[2 * m]     = va > 0.f ? va : expm1f(va);
            v[2 * m + 1] = vb > 0.f ? vb : expm1f(vb);
        }
        uint4 o;
        o.x = packbf(v[0], v[1]); o.y = packbf(v[2], v[3]);
        o.z = packbf(v[4], v[5]); o.w = packbf(v[6], v[7]);
        ((uint4*)(hmid_u + (size_t)d * 64))[lane] = o;
    }
}

// ---- gemm2 MFMA: h2pre[N,256](bf16) = hmid @ W2frag ; logits ----
__global__ void __launch_bounds__(256) gemm2_mfma_kernel(
        const __hip_bfloat16* __restrict__ hmid, const __hip_bfloat16* __restrict__ wfrag,
        const float* __restrict__ att_s, const float* __restrict__ att_d,
        __hip_bfloat16* __restrict__ h2pre, float* __restrict__ a_src, float* __restrict__ a_dst, int N) {
    int lane = threadIdx.x & 63, wv = threadIdx.x >> 6;
    int lo = lane & 15, quad = lane >> 4;
    int rowbase = (blockIdx.x * 4 + wv) * 16;
    if (rowbase >= N) return;
    int arow = rowbase + lo; if (arow >= N) arow = N - 1;
    const __hip_bfloat16* ap = hmid + (size_t)arow * 128 + quad * 8;
    floatx4 acc[16];
    #pragma unroll
    for (int nt = 0; nt < 16; ++nt) acc[nt] = (floatx4){0.f, 0.f, 0.f, 0.f};
    const short8* bf = (const short8*)wfrag;
    #pragma unroll
    for (int kt = 0; kt < 4; ++kt) {
        short8 a = *(const short8*)(ap + kt * 32);
        #pragma unroll
        for (int nt = 0; nt < 16; ++nt)
            acc[nt] = __builtin_amdgcn_mfma_f32_16x16x32_bf16(a, bf[(kt * 16 + nt) * 64 + lane], acc[nt], 0, 0, 0);
    }
    float ps0[4] = {0,0,0,0}, ps1[4] = {0,0,0,0}, pd0[4] = {0,0,0,0}, pd1[4] = {0,0,0,0};
    #pragma unroll
    for (int nt = 0; nt < 16; ++nt) {
        int ch = nt * 16 + lo;
        float as_v = att_s[ch], ad_v = att_d[ch];
        #pragma unroll
        for (int r = 0; r < 4; ++r) {
            int row = rowbase + quad * 4 + r;
            float val = acc[nt][r];
            if (row < N) ((unsigned short*)h2pre)[(size_t)row * 256 + ch] = bfbits(val);
            if (nt < 8) { ps0[r] += val * as_v; pd0[r] += val * ad_v; }
            else        { ps1[r] += val * as_v; pd1[r] += val * ad_v; }
        }
    }
    #pragma unroll
    for (int r = 0; r < 4; ++r) {
        int row = rowbase + quad * 4 + r;
        float v0 = ps0[r], v1 = ps1[r], v2 = pd0[r], v3 = pd1[r];
        #pragma unroll
        for (int off = 1; off < 16; off <<= 1) {
            v0 += __shfl_xor(v0, off, 64); v1 += __shfl_xor(v1, off, 64);
            v2 += __shfl_xor(v2, off, 64); v3 += __shfl_xor(v3, off, 64);
        }
        if (lo == 0 && row < N) {
            a_src[row * 2 + 0] = v0; a_src[row * 2 + 1] = v1;
            a_dst[row * 2 + 0] = v2; a_dst[row * 2 + 1] = v3;
        }
    }
}

// ---- agg2: wave/dst, single pass, inline exp, prefetched; head-mean+bias -> h2bf ----
__global__ void __launch_bounds__(256) agg2_csr_kernel(
        const int* __restrict__ row, const int* __restrict__ srcs,
        const float* __restrict__ a_src, const float* __restrict__ a_dst,
        const unsigned* __restrict__ h2u, const float* __restrict__ bias2,
        unsigned* __restrict__ h2bf_u, int N) {
    int d = blockIdx.x * 4 + (threadIdx.x >> 6);
    if (d >= N) return;
    int lane = threadIdx.x & 63;
    int beg = row[d], end = row[d + 1];
    int g = lane >> 5, q = lane & 31;
    float2 adp = ((const float2*)a_dst)[d];
    float den0 = 0.f, den1 = 0.f;
    v2f facc2[4];
    #pragma unroll
    for (int m = 0; m < 4; ++m) facc2[m] = (v2f){0.f, 0.f};
    for (int b = beg; b < end; b += 64) {
        int i = b + lane;
        int s = 0; float e0 = 0.f, e1 = 0.f;
        if (i < end) {
            s = srcs[i];
            float2 as = ((const float2*)a_src)[s];
            e0 = __expf(lrelu(as.x + adp.x));
            e1 = __expf(lrelu(as.y + adp.y));
            den0 += e0; den1 += e1;
        }
        int cnt = min(64, end - b);
        int rounds = (cnt + 1) >> 1;
        float w0 = __shfl(e0, g, 64);
        float w1 = __shfl(e1, g, 64);
        int   sj = __shfl(s,  g, 64);
        float wgt = (q < 16) ? w0 : w1;
        uint4 u = ((const uint4*)(h2u + (size_t)sj * 128))[q];
        for (int j = 0; j < rounds; ++j) {
            int sl2 = 2 * j + 2 + g; sl2 = sl2 > 63 ? 63 : sl2;
            float w0n = __shfl(e0, sl2, 64);
            float w1n = __shfl(e1, sl2, 64);
            int   sjn = __shfl(s,  sl2, 64);
            uint4 un = ((const uint4*)(h2u + (size_t)sjn * 128))[q];
            float wgtn = (q < 16) ? w0n : w1n;
            facc2[0] += bfpair(u.x) * wgt;
            facc2[1] += bfpair(u.y) * wgt;
            facc2[2] += bfpair(u.z) * wgt;
            facc2[3] += bfpair(u.w) * wgt;
            u = un; wgt = wgtn;
        }
    }
    den0 = wave_allreduce_sum(den0);
    den1 = wave_allreduce_sum(den1);
    float inv = (q < 16) ? 0.5f / (den0 + 1e-16f) : 0.5f / (den1 + 1e-16f);
    #pragma unroll
    for (int m = 0; m < 4; ++m) {
        facc2[m].x += __shfl_xor(facc2[m].x, 32, 64);  // combine edge-parity groups
        facc2[m].y += __shfl_xor(facc2[m].y, 32, 64);
        facc2[m] *= inv;                               // normalize + fold head-mean
        facc2[m].x += __shfl_xor(facc2[m].x, 16, 64);  // combine heads
        facc2[m].y += __shfl_xor(facc2[m].y, 16, 64);
    }
    if (lane < 16) {
        int c0 = 8 * lane;
        uint4 o;
        o.x = packbf(facc2[0].x + bias2[c0 + 0], facc2[0].y + bias2[c0 + 1]);
        o.y = packbf(facc2[1].x + bias2[c0 + 2], facc2[1].y + bias2[c0 + 3]);
        o.z = packbf(facc2[2].x + bias2[c0 + 4], facc2[2].y + bias2[c0 + 5]);
        o.w = packbf(facc2[3].x + bias2[c0 + 6], facc2[3].y + bias2[c0 + 7]);
        ((uint4*)(h2bf_u + (size_t)d * 64))[lane] = o;
    }
}

// ---- zsd MFMA: zsd[N,256](bf16): [zs | zd + fc2_b] = h2bf @ fc2frag ----
__global__ void __launch_bounds__(256) zsd_mfma_kernel(
        const __hip_bfloat16* __restrict__ h2bf, const __hip_bfloat16* __restrict__ wfrag,
        const float* __restrict__ fc2_b, __hip_bfloat16* __restrict__ zsd, int N) {
    int lane = threadIdx.x & 63, wv = threadIdx.x >> 6;
    int lo = lane & 15, quad = lane >> 4;
    int rowbase = (blockIdx.x * 4 + wv) * 16;
    if (rowbase >= N) return;
    int arow = rowbase + lo; if (arow >= N) arow = N - 1;
    const __hip_bfloat16* ap = h2bf + (size_t)arow * 128 + quad * 8;
    floatx4 acc[16];
    #pragma unroll
    for (int nt = 0; nt < 16; ++nt) acc[nt] = (floatx4){0.f, 0.f, 0.f, 0.f};
    const short8* bf = (const short8*)wfrag;
    #pragma unroll
    for (int kt = 0; kt < 4; ++kt) {
        short8 a = *(const short8*)(ap + kt * 32);
        #pragma unroll
        for (int nt = 0; nt < 16; ++nt)
            acc[nt] = __builtin_amdgcn_mfma_f32_16x16x32_bf16(a, bf[(kt * 16 + nt) * 64 + lane], acc[nt], 0, 0, 0);
    }
    #pragma unroll
    for (int nt = 0; nt < 16; ++nt) {
        int ch = nt * 16 + lo;
        float bv = (nt >= 8) ? fc2_b[ch - 128] : 0.f;
        #pragma unroll
        for (int r = 0; r < 4; ++r) {
            int row = rowbase + quad * 4 + r;
            if (row < N) ((unsigned short*)zsd)[(size_t)row * 256 + ch] = bfbits(acc[nt][r] + bv);
        }
    }
}

// ---- edge head: 2 edges/round, 8 rounds/wave; channel-split (no duplicate work) ----
__global__ void __launch_bounds__(256) edge_zsd_kernel(
        const int* __restrict__ src, const int* __restrict__ dst,
        const unsigned* __restrict__ zsd_u, const float* __restrict__ fc3_w,
        const float* __restrict__ fc3_b, float* __restrict__ out, int E) {
    int lane = threadIdx.x & 63, wv = threadIdx.x >> 6;
    int g = lane >> 5, r = (lane >> 4) & 1, q = lane & 15;
    int base = (blockIdx.x * 4 + wv) * 16;
    if (base >= E) return;
    v2f f30 = {fc3_w[8 * q + 4 * r + 0], fc3_w[8 * q + 4 * r + 1]};
    v2f f31 = {fc3_w[8 * q + 4 * r + 2], fc3_w[8 * q + 4 * r + 3]};
    float b3 = fc3_b[0];
    #pragma unroll
    for (int j = 0; j < 8; ++j) {
        int e = base + 2 * j + g;
        int ec = e < E ? e : E - 1;
        int node = r ? dst[ec] : src[ec];
        uint4 mine = ((const uint4*)(zsd_u + (size_t)node * 128 + (r << 6)))[q];
        unsigned sx = (unsigned)__shfl_xor((int)mine.x, 16, 64);
        unsigned sy = (unsigned)__shfl_xor((int)mine.y, 16, 64);
        unsigned sz = (unsigned)__shfl_xor((int)mine.z, 16, 64);
        unsigned sw = (unsigned)__shfl_xor((int)mine.w, 16, 64);
        unsigned mA = r ? mine.z : mine.x;
        unsigned mB = r ? mine.w : mine.y;
        unsigned oA = r ? sz : sx;
        unsigned oB = r ? sw : sy;
        v2f sA = bfpair(mA) + bfpair(oA);
        v2f sB = bfpair(mB) + bfpair(oB);
        sA.x = fmaxf(sA.x, 0.f); sA.y = fmaxf(sA.y, 0.f);
        sB.x = fmaxf(sB.x, 0.f); sB.y = fmaxf(sB.y, 0.f);
        v2f p2 = sA * f30 + sB * f31;
        float p = p2.x + p2.y;
        #pragma unroll
        for (int off = 1; off < 32; off <<= 1) p += __shfl_xor(p, off, 64);
        if ((lane & 31) == 0 && e < E)
            out[e] = 1.f / (1.f + expf(-(p + b3)));
    }
}

extern "C" void kernel_launch(void* const* d_in, const int* in_sizes, int n_in,
                              void* d_out, int out_size, void* d_ws, size_t ws_size,
                              hipStream_t stream) {
    const float* x      = (const float*)d_in[0];
    const int*   ei     = (const int*)d_in[1];
    const float* cls    = (const float*)d_in[2];
    const float* fc0_w  = (const float*)d_in[3];
    const float* fc0_b  = (const float*)d_in[4];
    const float* W1     = (const float*)d_in[5];
    const float* att_s1 = (const float*)d_in[6];
    const float* att_d1 = (const float*)d_in[7];
    const float* bias1  = (const float*)d_in[8];
    const float* W2     = (const float*)d_in[9];
    const float* att_s2 = (const float*)d_in[10];
    const float* att_d2 = (const float*)d_in[11];
    const float* bias2  = (const float*)d_in[12];
    const float* fc2_w  = (const float*)d_in[13];
    const float* fc2_b  = (const float*)d_in[14];
    const float* fc3_w  = (const float*)d_in[15];
    const float* fc3_b  = (const float*)d_in[16];
    float* out = (float*)d_out;

    int N = in_sizes[0] / 128;
    int E = in_sizes[1] / 2;
    const int* src = ei;
    const int* dst = ei + E;

    float* w = (float*)d_ws;
    size_t off = 0;
    auto alloc = [&](size_t n) { float* p = w + off; off += (n + 63) & ~(size_t)63; return p; };
    float* c1      = alloc(128);
    float* w1fragf = alloc(16384 / 2);
    float* w2fragf = alloc(32768 / 2);
    float* fc2fragf= alloc(32768 / 2);
    float* a_s1    = alloc((size_t)N * 2);
    float* a_d1    = alloc((size_t)N * 2);
    float* a_s2    = alloc((size_t)N * 2);
    float* a_d2    = alloc((size_t)N * 2);
    float* h1bff   = alloc((size_t)N * 64);   // N*128 bf16
    float* hmidf   = alloc((size_t)N * 64);   // N*128 bf16
    float* h2pref  = alloc((size_t)N * 128);  // N*256 bf16
    float* h2bff   = alloc((size_t)N * 64);   // N*128 bf16
    float* zsdf    = alloc((size_t)N * 128);  // N*256 bf16
    int* counts = (int*)alloc(N);
    int* rowp   = (int*)alloc(N + 1);
    int* woff   = (int*)alloc(N);
    int* srcs   = (int*)alloc(E);
    __hip_bfloat16* w1frag = (__hip_bfloat16*)w1fragf;
    __hip_bfloat16* w2frag = (__hip_bfloat16*)w2fragf;
    __hip_bfloat16* fc2frag= (__hip_bfloat16*)fc2fragf;
    __hip_bfloat16* hmid   = (__hip_bfloat16*)hmidf;
    __hip_bfloat16* h2pre  = (__hip_bfloat16*)h2pref;
    __hip_bfloat16* h2bf   = (__hip_bfloat16*)h2bff;
    __hip_bfloat16* h1bf   = (__hip_bfloat16*)h1bff;
    __hip_bfloat16* zsd    = (__hip_bfloat16*)zsdf;

    hipMemsetAsync(counts, 0, sizeof(int) * (size_t)N, stream);

    prep_kernel<<<64, 256, 0, stream>>>(cls, fc0_w, fc0_b, W1, W2, fc2_w, c1, w1frag, w2frag, fc2frag);
    count_kernel<<<(E + 255) / 256, 256, 0, stream>>>(dst, counts, E);
    scan_kernel<<<1, 1024, 0, stream>>>(counts, rowp, woff, N, E);
    scatter_kernel<<<(E + 255) / 256, 256, 0, stream>>>(src, dst, woff, srcs, E);
    gemm1_mfma_kernel<<<(N + 63) / 64, 256, 0, stream>>>(x, w1frag, c1, att_s1, att_d1, h1bf, a_s1, a_d1, N);
    agg1_csr_kernel<<<(N + 3) / 4, 256, 0, stream>>>(rowp, srcs, a_s1, a_d1, (const unsigned*)h1bf, bias1, (unsigned*)hmid, N);
    gemm2_mfma_kernel<<<(N + 63) / 64, 256, 0, stream>>>(hmid, w2frag, att_s2, att_d2, h2pre, a_s2, a_d2, N);
    agg2_csr_kernel<<<(N + 3) / 4, 256, 0, stream>>>(rowp, srcs, a_s2, a_d2, (const unsigned*)h2pre, bias2, (unsigned*)h2bf, N);
    zsd_mfma_kernel<<<(N + 63) / 64, 256, 0, stream>>>(h2bf, fc2frag, fc2_b, zsd, N);
    edge_zsd_kernel<<<(E + 63) / 64, 256, 0, stream>>>(src, dst, (const unsigned*)zsd, fc3_w, fc3_b, out, E);
}

// Round 8
// 360.966 us; speedup vs baseline: 1.1262x; 1.1262x over previous
//
#include <hip/hip_runtime.h>
#include <hip/hip_bf16.h>
#include <math.h>

// N=50000, E=500000, SED=128, HID=64, H=2, F_node=128
// Round 8: Round 7 (single-pass inline-exp agg, prefetched gathers, packed fma,
// dedup edge head) + hierarchical 3-kernel scan (Round 5) instead of the
// 49.7us single-block scan.

typedef short short8 __attribute__((ext_vector_type(8)));
typedef float floatx4 __attribute__((ext_vector_type(4)));
typedef float v2f __attribute__((ext_vector_type(2)));
typedef unsigned uint2v __attribute__((ext_vector_type(2)));

__device__ __forceinline__ float wave_allreduce_sum(float v) {
    #pragma unroll
    for (int off = 1; off < 64; off <<= 1) v += __shfl_xor(v, off, 64);
    return v;
}
__device__ __forceinline__ v2f bfpair(unsigned v) {
    uint2v t; t.x = v << 16; t.y = v & 0xFFFF0000u;
    return __builtin_bit_cast(v2f, t);
}
__device__ __forceinline__ unsigned short bfbits(float f) {
    return __builtin_bit_cast(unsigned short, __float2bfloat16(f));
}
__device__ __forceinline__ unsigned packbf(float a, float b) {
    return ((unsigned)bfbits(b) << 16) | (unsigned)bfbits(a);
}
__device__ __forceinline__ float lrelu(float v) { return v > 0.f ? v : 0.2f * v; }

// ---- prep: sent/c1; bf16 B-fragment tables for W1, W2, fc2(split) ----
__global__ void prep_kernel(const float* __restrict__ cls, const float* __restrict__ fc0_w,
                            const float* __restrict__ fc0_b, const float* __restrict__ W1,
                            const float* __restrict__ W2, const float* __restrict__ fc2_w,
                            float* __restrict__ c1,
                            __hip_bfloat16* __restrict__ w1frag,
                            __hip_bfloat16* __restrict__ w2frag,
                            __hip_bfloat16* __restrict__ fc2frag) {
    int tid = threadIdx.x;
    if (blockIdx.x == 0) {
        __shared__ float s_sent[128];
        if (tid < 128) {
            float acc = fc0_b[tid];
            const float* row = fc0_w + (size_t)tid * 768;
            for (int k = 0; k < 768; ++k) acc += row[k] * cls[k];
            s_sent[tid] = acc;
        }
        __syncthreads();
        if (tid < 128) {
            float acc = 0.f;
            for (int k = 0; k < 128; ++k) acc += s_sent[k] * W1[(128 + k) * 128 + tid];
            c1[tid] = acc;
        }
    }
    int gstride = gridDim.x * blockDim.x;
    int g = blockIdx.x * blockDim.x + tid;
    for (int i = g; i < 16384; i += gstride) {
        int j = i & 7, l = (i >> 3) & 63, nt = (i >> 9) & 7, kt = (i >> 12) & 3;
        int k = kt * 32 + (l >> 4) * 8 + j;
        int n = nt * 16 + (l & 15);
        w1frag[i] = __float2bfloat16(W1[k * 128 + n]);
    }
    for (int i = g; i < 32768; i += gstride) {
        int j = i & 7, l = (i >> 3) & 63, nt = (i >> 9) & 15, kt = (i >> 13) & 3;
        int k = kt * 32 + (l >> 4) * 8 + j;
        int n = nt * 16 + (l & 15);
        w2frag[i] = __float2bfloat16(W2[k * 256 + n]);
    }
    for (int i = g; i < 32768; i += gstride) {
        int j = i & 7, l = (i >> 3) & 63, nt = (i >> 9) & 15, kt = (i >> 13) & 3;
        int k = kt * 32 + (l >> 4) * 8 + j;
        int n = nt * 16 + (l & 15);
        float v = (n < 128) ? fc2_w[n * 256 + k] : fc2_w[(n - 128) * 256 + 128 + k];
        fc2frag[i] = __float2bfloat16(v);
    }
}

// ---- CSR build ----
__global__ void count_kernel(const int* __restrict__ dst, int* __restrict__ counts, int E) {
    int e = blockIdx.x * blockDim.x + threadIdx.x;
    if (e < E) atomicAdd(&counts[dst[e]], 1);
}

__global__ void __launch_bounds__(256) bsum_kernel(const int* __restrict__ counts,
                                                   int* __restrict__ bsum, int N) {
    int base = blockIdx.x * 1024;
    int tid = threadIdx.x;
    int v = 0;
    #pragma unroll
    for (int k = 0; k < 4; ++k) {
        int idx = base + k * 256 + tid;
        if (idx < N) v += counts[idx];
    }
    #pragma unroll
    for (int off = 1; off < 64; off <<= 1) v += __shfl_xor(v, off, 64);
    __shared__ int ws[4];
    if ((tid & 63) == 0) ws[tid >> 6] = v;
    __syncthreads();
    if (tid == 0) bsum[blockIdx.x] = ws[0] + ws[1] + ws[2] + ws[3];
}

__global__ void top_scan_kernel(const int* __restrict__ bsum, int* __restrict__ boff, int nb) {
    int lane = threadIdx.x;
    int v = (lane < nb) ? bsum[lane] : 0;
    int x = v;
    #pragma unroll
    for (int off = 1; off < 64; off <<= 1) {
        int t = __shfl_up(x, off, 64);
        if (lane >= off) x += t;
    }
    if (lane < nb) boff[lane] = x - v;
}

__global__ void __launch_bounds__(1024) local_scan_kernel(const int* __restrict__ counts,
                                                          const int* __restrict__ boff,
                                                          int* __restrict__ row, int* __restrict__ woff,
                                                          int N, int E) {
    int tid = threadIdx.x, lane = tid & 63, wv = tid >> 6;
    int base = blockIdx.x * 1024;
    __shared__ int wsum[16];
    int v = (base + tid < N) ? counts[base + tid] : 0;
    int x = v;
    #pragma unroll
    for (int off = 1; off < 64; off <<= 1) {
        int t = __shfl_up(x, off, 64);
        if (lane >= off) x += t;
    }
    if (lane == 63) wsum[wv] = x;
    __syncthreads();
    if (wv == 0 && lane < 16) {
        int y = wsum[lane];
        #pragma unroll
        for (int off = 1; off < 16; off <<= 1) {
            int t = __shfl_up(y, off, 64);
            if (lane >= off) y += t;
        }
        wsum[lane] = y;
    }
    __syncthreads();
    int excl = boff[blockIdx.x] + (wv ? wsum[wv - 1] : 0) + x - v;
    if (base + tid < N) { row[base + tid] = excl; woff[base + tid] = excl; }
    if (blockIdx.x == 0 && tid == 0) row[N] = E;
}

__global__ void scatter_kernel(const int* __restrict__ src, const int* __restrict__ dst,
                               int* __restrict__ woff, int* __restrict__ srcs, int E) {
    int e = blockIdx.x * blockDim.x + threadIdx.x;
    if (e < E) {
        int pos = atomicAdd(&woff[dst[e]], 1);
        srcs[pos] = src[e];
    }
}

// ---- gemm1 MFMA (cvt fused): h1bf = bf16(x) @ W1frag + c1 ; logits ----
__global__ void __launch_bounds__(256) gemm1_mfma_kernel(
        const float* __restrict__ x, const __hip_bfloat16* __restrict__ wfrag,
        const float* __restrict__ c1, const float* __restrict__ att_s, const float* __restrict__ att_d,
        __hip_bfloat16* __restrict__ h1bf, float* __restrict__ a_src, float* __restrict__ a_dst, int N) {
    int lane = threadIdx.x & 63, wv = threadIdx.x >> 6;
    int lo = lane & 15, quad = lane >> 4;
    int rowbase = (blockIdx.x * 4 + wv) * 16;
    if (rowbase >= N) return;
    int arow = rowbase + lo; if (arow >= N) arow = N - 1;
    const float* ap = x + (size_t)arow * 128 + quad * 8;
    floatx4 acc[8];
    #pragma unroll
    for (int nt = 0; nt < 8; ++nt) acc[nt] = (floatx4){0.f, 0.f, 0.f, 0.f};
    const short8* bf = (const short8*)wfrag;
    #pragma unroll
    for (int kt = 0; kt < 4; ++kt) {
        float4 fa = *(const float4*)(ap + kt * 32);
        float4 fb = *(const float4*)(ap + kt * 32 + 4);
        short8 a;
        a[0] = (short)bfbits(fa.x); a[1] = (short)bfbits(fa.y);
        a[2] = (short)bfbits(fa.z); a[3] = (short)bfbits(fa.w);
        a[4] = (short)bfbits(fb.x); a[5] = (short)bfbits(fb.y);
        a[6] = (short)bfbits(fb.z); a[7] = (short)bfbits(fb.w);
        #pragma unroll
        for (int nt = 0; nt < 8; ++nt)
            acc[nt] = __builtin_amdgcn_mfma_f32_16x16x32_bf16(a, bf[(kt * 8 + nt) * 64 + lane], acc[nt], 0, 0, 0);
    }
    float ps0[4] = {0,0,0,0}, ps1[4] = {0,0,0,0}, pd0[4] = {0,0,0,0}, pd1[4] = {0,0,0,0};
    #pragma unroll
    for (int nt = 0; nt < 8; ++nt) {
        int ch = nt * 16 + lo;
        float cv = c1[ch], as_v = att_s[ch], ad_v = att_d[ch];
        #pragma unroll
        for (int r = 0; r < 4; ++r) {
            int row = rowbase + quad * 4 + r;
            float val = acc[nt][r] + cv;
            if (row < N) ((unsigned short*)h1bf)[(size_t)row * 128 + ch] = bfbits(val);
            if (nt < 4) { ps0[r] += val * as_v; pd0[r] += val * ad_v; }
            else        { ps1[r] += val * as_v; pd1[r] += val * ad_v; }
        }
    }
    #pragma unroll
    for (int r = 0; r < 4; ++r) {
        int row = rowbase + quad * 4 + r;
        float v0 = ps0[r], v1 = ps1[r], v2 = pd0[r], v3 = pd1[r];
        #pragma unroll
        for (int off = 1; off < 16; off <<= 1) {
            v0 += __shfl_xor(v0, off, 64); v1 += __shfl_xor(v1, off, 64);
            v2 += __shfl_xor(v2, off, 64); v3 += __shfl_xor(v3, off, 64);
        }
        if (lo == 0 && row < N) {
            a_src[row * 2 + 0] = v0; a_src[row * 2 + 1] = v1;
            a_dst[row * 2 + 0] = v2; a_dst[row * 2 + 1] = v3;
        }
    }
}

// ---- agg1: wave/dst, single pass, inline exp, prefetched rounds; ELU -> hmid bf16 ----
__global__ void __launch_bounds__(256) agg1_csr_kernel(
        const int* __restrict__ row, const int* __restrict__ srcs,
        const float* __restrict__ a_src, const float* __restrict__ a_dst,
        const unsigned* __restrict__ h1u, const float* __restrict__ bias1,
        unsigned* __restrict__ hmid_u, int N) {
    int d = blockIdx.x * 4 + (threadIdx.x >> 6);
    if (d >= N) return;
    int lane = threadIdx.x & 63;
    int beg = row[d], end = row[d + 1];
    int g = lane >> 4, q = lane & 15;
    float2 adp = ((const float2*)a_dst)[d];
    float den0 = 0.f, den1 = 0.f;
    v2f facc2[4];
    #pragma unroll
    for (int m = 0; m < 4; ++m) facc2[m] = (v2f){0.f, 0.f};
    for (int b = beg; b < end; b += 64) {
        int i = b + lane;
        int s = 0; float e0 = 0.f, e1 = 0.f;
        if (i < end) {
            s = srcs[i];
            float2 as = ((const float2*)a_src)[s];
            e0 = __expf(lrelu(as.x + adp.x));
            e1 = __expf(lrelu(as.y + adp.y));
            den0 += e0; den1 += e1;
        }
        int cnt = min(64, end - b);
        int rounds = (cnt + 3) >> 2;
        float w0 = __shfl(e0, g, 64);
        float w1 = __shfl(e1, g, 64);
        int   sj = __shfl(s,  g, 64);
        float wgt = (q < 8) ? w0 : w1;
        uint4 u = ((const uint4*)(h1u + (size_t)sj * 64))[q];
        for (int j = 0; j < rounds; ++j) {
            int sl2 = 4 * j + 4 + g; sl2 = sl2 > 63 ? 63 : sl2;
            float w0n = __shfl(e0, sl2, 64);
            float w1n = __shfl(e1, sl2, 64);
            int   sjn = __shfl(s,  sl2, 64);
            uint4 un = ((const uint4*)(h1u + (size_t)sjn * 64))[q];
            float wgtn = (q < 8) ? w0n : w1n;
            facc2[0] += bfpair(u.x) * wgt;
            facc2[1] += bfpair(u.y) * wgt;
            facc2[2] += bfpair(u.z) * wgt;
            facc2[3] += bfpair(u.w) * wgt;
            u = un; wgt = wgtn;
        }
    }
    den0 = wave_allreduce_sum(den0);
    den1 = wave_allreduce_sum(den1);
    #pragma unroll
    for (int m = 0; m < 4; ++m) {
        facc2[m].x += __shfl_xor(facc2[m].x, 16, 64);
        facc2[m].y += __shfl_xor(facc2[m].y, 16, 64);
        facc2[m].x += __shfl_xor(facc2[m].x, 32, 64);
        facc2[m].y += __shfl_xor(facc2[m].y, 32, 64);
    }
    if (lane < 16) {
        float inv = (lane < 8) ? 1.f / (den0 + 1e-16f) : 1.f / (den1 + 1e-16f);
        int c0 = 8 * lane;
        float v[8];
        #pragma unroll
        for (int m = 0; m < 4; ++m) {
            float va = facc2[m].x * inv + bias1[c0 + 2 * m];
            float vb = facc2[m].y * inv + bias1[c0 + 2 * m + 1];
            v[2 * m]     = va > 0.f ? va : expm1f(va);
            v[2 * m + 1] = vb > 0.f ? vb : expm1f(vb);
        }
        uint4 o;
        o.x = packbf(v[0], v[1]); o.y = packbf(v[2], v[3]);
        o.z = packbf(v[4], v[5]); o.w = packbf(v[6], v[7]);
        ((uint4*)(hmid_u + (size_t)d * 64))[lane] = o;
    }
}

// ---- gemm2 MFMA: h2pre[N,256](bf16) = hmid @ W2frag ; logits ----
__global__ void __launch_bounds__(256) gemm2_mfma_kernel(
        const __hip_bfloat16* __restrict__ hmid, const __hip_bfloat16* __restrict__ wfrag,
        const float* __restrict__ att_s, const float* __restrict__ att_d,
        __hip_bfloat16* __restrict__ h2pre, float* __restrict__ a_src, float* __restrict__ a_dst, int N) {
    int lane = threadIdx.x & 63, wv = threadIdx.x >> 6;
    int lo = lane & 15, quad = lane >> 4;
    int rowbase = (blockIdx.x * 4 + wv) * 16;
    if (rowbase >= N) return;
    int arow = rowbase + lo; if (arow >= N) arow = N - 1;
    const __hip_bfloat16* ap = hmid + (size_t)arow * 128 + quad * 8;
    floatx4 acc[16];
    #pragma unroll
    for (int nt = 0; nt < 16; ++nt) acc[nt] = (floatx4){0.f, 0.f, 0.f, 0.f};
    const short8* bf = (const short8*)wfrag;
    #pragma unroll
    for (int kt = 0; kt < 4; ++kt) {
        short8 a = *(const short8*)(ap + kt * 32);
        #pragma unroll
        for (int nt = 0; nt < 16; ++nt)
            acc[nt] = __builtin_amdgcn_mfma_f32_16x16x32_bf16(a, bf[(kt * 16 + nt) * 64 + lane], acc[nt], 0, 0, 0);
    }
    float ps0[4] = {0,0,0,0}, ps1[4] = {0,0,0,0}, pd0[4] = {0,0,0,0}, pd1[4] = {0,0,0,0};
    #pragma unroll
    for (int nt = 0; nt < 16; ++nt) {
        int ch = nt * 16 + lo;
        float as_v = att_s[ch], ad_v = att_d[ch];
        #pragma unroll
        for (int r = 0; r < 4; ++r) {
            int row = rowbase + quad * 4 + r;
            float val = acc[nt][r];
            if (row < N) ((unsigned short*)h2pre)[(size_t)row * 256 + ch] = bfbits(val);
            if (nt < 8) { ps0[r] += val * as_v; pd0[r] += val * ad_v; }
            else        { ps1[r] += val * as_v; pd1[r] += val * ad_v; }
        }
    }
    #pragma unroll
    for (int r = 0; r < 4; ++r) {
        int row = rowbase + quad * 4 + r;
        float v0 = ps0[r], v1 = ps1[r], v2 = pd0[r], v3 = pd1[r];
        #pragma unroll
        for (int off = 1; off < 16; off <<= 1) {
            v0 += __shfl_xor(v0, off, 64); v1 += __shfl_xor(v1, off, 64);
            v2 += __shfl_xor(v2, off, 64); v3 += __shfl_xor(v3, off, 64);
        }
        if (lo == 0 && row < N) {
            a_src[row * 2 + 0] = v0; a_src[row * 2 + 1] = v1;
            a_dst[row * 2 + 0] = v2; a_dst[row * 2 + 1] = v3;
        }
    }
}

// ---- agg2: wave/dst, single pass, inline exp, prefetched; head-mean+bias -> h2bf ----
__global__ void __launch_bounds__(256) agg2_csr_kernel(
        const int* __restrict__ row, const int* __restrict__ srcs,
        const float* __restrict__ a_src, const float* __restrict__ a_dst,
        const unsigned* __restrict__ h2u, const float* __restrict__ bias2,
        unsigned* __restrict__ h2bf_u, int N) {
    int d = blockIdx.x * 4 + (threadIdx.x >> 6);
    if (d >= N) return;
    int lane = threadIdx.x & 63;
    int beg = row[d], end = row[d + 1];
    int g = lane >> 5, q = lane & 31;
    float2 adp = ((const float2*)a_dst)[d];
    float den0 = 0.f, den1 = 0.f;
    v2f facc2[4];
    #pragma unroll
    for (int m = 0; m < 4; ++m) facc2[m] = (v2f){0.f, 0.f};
    for (int b = beg; b < end; b += 64) {
        int i = b + lane;
        int s = 0; float e0 = 0.f, e1 = 0.f;
        if (i < end) {
            s = srcs[i];
            float2 as = ((const float2*)a_src)[s];
            e0 = __expf(lrelu(as.x + adp.x));
            e1 = __expf(lrelu(as.y + adp.y));
            den0 += e0; den1 += e1;
        }
        int cnt = min(64, end - b);
        int rounds = (cnt + 1) >> 1;
        float w0 = __shfl(e0, g, 64);
        float w1 = __shfl(e1, g, 64);
        int   sj = __shfl(s,  g, 64);
        float wgt = (q < 16) ? w0 : w1;
        uint4 u = ((const uint4*)(h2u + (size_t)sj * 128))[q];
        for (int j = 0; j < rounds; ++j) {
            int sl2 = 2 * j + 2 + g; sl2 = sl2 > 63 ? 63 : sl2;
            float w0n = __shfl(e0, sl2, 64);
            float w1n = __shfl(e1, sl2, 64);
            int   sjn = __shfl(s,  sl2, 64);
            uint4 un = ((const uint4*)(h2u + (size_t)sjn * 128))[q];
            float wgtn = (q < 16) ? w0n : w1n;
            facc2[0] += bfpair(u.x) * wgt;
            facc2[1] += bfpair(u.y) * wgt;
            facc2[2] += bfpair(u.z) * wgt;
            facc2[3] += bfpair(u.w) * wgt;
            u = un; wgt = wgtn;
        }
    }
    den0 = wave_allreduce_sum(den0);
    den1 = wave_allreduce_sum(den1);
    float inv = (q < 16) ? 0.5f / (den0 + 1e-16f) : 0.5f / (den1 + 1e-16f);
    #pragma unroll
    for (int m = 0; m < 4; ++m) {
        facc2[m].x += __shfl_xor(facc2[m].x, 32, 64);
        facc2[m].y += __shfl_xor(facc2[m].y, 32, 64);
        facc2[m] *= inv;
        facc2[m].x += __shfl_xor(facc2[m].x, 16, 64);
        facc2[m].y += __shfl_xor(facc2[m].y, 16, 64);
    }
    if (lane < 16) {
        int c0 = 8 * lane;
        uint4 o;
        o.x = packbf(facc2[0].x + bias2[c0 + 0], facc2[0].y + bias2[c0 + 1]);
        o.y = packbf(facc2[1].x + bias2[c0 + 2], facc2[1].y + bias2[c0 + 3]);
        o.z = packbf(facc2[2].x + bias2[c0 + 4], facc2[2].y + bias2[c0 + 5]);
        o.w = packbf(facc2[3].x + bias2[c0 + 6], facc2[3].y + bias2[c0 + 7]);
        ((uint4*)(h2bf_u + (size_t)d * 64))[lane] = o;
    }
}

// ---- zsd MFMA: zsd[N,256](bf16): [zs | zd + fc2_b] = h2bf @ fc2frag ----
__global__ void __launch_bounds__(256) zsd_mfma_kernel(
        const __hip_bfloat16* __restrict__ h2bf, const __hip_bfloat16* __restrict__ wfrag,
        const float* __restrict__ fc2_b, __hip_bfloat16* __restrict__ zsd, int N) {
    int lane = threadIdx.x & 63, wv = threadIdx.x >> 6;
    int lo = lane & 15, quad = lane >> 4;
    int rowbase = (blockIdx.x * 4 + wv) * 16;
    if (rowbase >= N) return;
    int arow = rowbase + lo; if (arow >= N) arow = N - 1;
    const __hip_bfloat16* ap = h2bf + (size_t)arow * 128 + quad * 8;
    floatx4 acc[16];
    #pragma unroll
    for (int nt = 0; nt < 16; ++nt) acc[nt] = (floatx4){0.f, 0.f, 0.f, 0.f};
    const short8* bf = (const short8*)wfrag;
    #pragma unroll
    for (int kt = 0; kt < 4; ++kt) {
        short8 a = *(const short8*)(ap + kt * 32);
        #pragma unroll
        for (int nt = 0; nt < 16; ++nt)
            acc[nt] = __builtin_amdgcn_mfma_f32_16x16x32_bf16(a, bf[(kt * 16 + nt) * 64 + lane], acc[nt], 0, 0, 0);
    }
    #pragma unroll
    for (int nt = 0; nt < 16; ++nt) {
        int ch = nt * 16 + lo;
        float bv = (nt >= 8) ? fc2_b[ch - 128] : 0.f;
        #pragma unroll
        for (int r = 0; r < 4; ++r) {
            int row = rowbase + quad * 4 + r;
            if (row < N) ((unsigned short*)zsd)[(size_t)row * 256 + ch] = bfbits(acc[nt][r] + bv);
        }
    }
}

// ---- edge head: 2 edges/round, 8 rounds/wave; channel-split ----
__global__ void __launch_bounds__(256) edge_zsd_kernel(
        const int* __restrict__ src, const int* __restrict__ dst,
        const unsigned* __restrict__ zsd_u, const float* __restrict__ fc3_w,
        const float* __restrict__ fc3_b, float* __restrict__ out, int E) {
    int lane = threadIdx.x & 63, wv = threadIdx.x >> 6;
    int g = lane >> 5, r = (lane >> 4) & 1, q = lane & 15;
    int base = (blockIdx.x * 4 + wv) * 16;
    if (base >= E) return;
    v2f f30 = {fc3_w[8 * q + 4 * r + 0], fc3_w[8 * q + 4 * r + 1]};
    v2f f31 = {fc3_w[8 * q + 4 * r + 2], fc3_w[8 * q + 4 * r + 3]};
    float b3 = fc3_b[0];
    #pragma unroll
    for (int j = 0; j < 8; ++j) {
        int e = base + 2 * j + g;
        int ec = e < E ? e : E - 1;
        int node = r ? dst[ec] : src[ec];
        uint4 mine = ((const uint4*)(zsd_u + (size_t)node * 128 + (r << 6)))[q];
        unsigned sx = (unsigned)__shfl_xor((int)mine.x, 16, 64);
        unsigned sy = (unsigned)__shfl_xor((int)mine.y, 16, 64);
        unsigned sz = (unsigned)__shfl_xor((int)mine.z, 16, 64);
        unsigned sw = (unsigned)__shfl_xor((int)mine.w, 16, 64);
        unsigned mA = r ? mine.z : mine.x;
        unsigned mB = r ? mine.w : mine.y;
        unsigned oA = r ? sz : sx;
        unsigned oB = r ? sw : sy;
        v2f sA = bfpair(mA) + bfpair(oA);
        v2f sB = bfpair(mB) + bfpair(oB);
        sA.x = fmaxf(sA.x, 0.f); sA.y = fmaxf(sA.y, 0.f);
        sB.x = fmaxf(sB.x, 0.f); sB.y = fmaxf(sB.y, 0.f);
        v2f p2 = sA * f30 + sB * f31;
        float p = p2.x + p2.y;
        #pragma unroll
        for (int off = 1; off < 32; off <<= 1) p += __shfl_xor(p, off, 64);
        if ((lane & 31) == 0 && e < E)
            out[e] = 1.f / (1.f + expf(-(p + b3)));
    }
}

extern "C" void kernel_launch(void* const* d_in, const int* in_sizes, int n_in,
                              void* d_out, int out_size, void* d_ws, size_t ws_size,
                              hipStream_t stream) {
    const float* x      = (const float*)d_in[0];
    const int*   ei     = (const int*)d_in[1];
    const float* cls    = (const float*)d_in[2];
    const float* fc0_w  = (const float*)d_in[3];
    const float* fc0_b  = (const float*)d_in[4];
    const float* W1     = (const float*)d_in[5];
    const float* att_s1 = (const float*)d_in[6];
    const float* att_d1 = (const float*)d_in[7];
    const float* bias1  = (const float*)d_in[8];
    const float* W2     = (const float*)d_in[9];
    const float* att_s2 = (const float*)d_in[10];
    const float* att_d2 = (const float*)d_in[11];
    const float* bias2  = (const float*)d_in[12];
    const float* fc2_w  = (const float*)d_in[13];
    const float* fc2_b  = (const float*)d_in[14];
    const float* fc3_w  = (const float*)d_in[15];
    const float* fc3_b  = (const float*)d_in[16];
    float* out = (float*)d_out;

    int N = in_sizes[0] / 128;
    int E = in_sizes[1] / 2;
    const int* src = ei;
    const int* dst = ei + E;
    int nb = (N + 1023) / 1024;

    float* w = (float*)d_ws;
    size_t off = 0;
    auto alloc = [&](size_t n) { float* p = w + off; off += (n + 63) & ~(size_t)63; return p; };
    float* c1      = alloc(128);
    float* w1fragf = alloc(16384 / 2);
    float* w2fragf = alloc(32768 / 2);
    float* fc2fragf= alloc(32768 / 2);
    float* a_s1    = alloc((size_t)N * 2);
    float* a_d1    = alloc((size_t)N * 2);
    float* a_s2    = alloc((size_t)N * 2);
    float* a_d2    = alloc((size_t)N * 2);
    float* h1bff   = alloc((size_t)N * 64);   // N*128 bf16
    float* hmidf   = alloc((size_t)N * 64);   // N*128 bf16
    float* h2pref  = alloc((size_t)N * 128);  // N*256 bf16
    float* h2bff   = alloc((size_t)N * 64);   // N*128 bf16
    float* zsdf    = alloc((size_t)N * 128);  // N*256 bf16
    int* counts = (int*)alloc(N);
    int* rowp   = (int*)alloc(N + 1);
    int* woff   = (int*)alloc(N);
    int* srcs   = (int*)alloc(E);
    int* bsum   = (int*)alloc(64);
    int* boff   = (int*)alloc(64);
    __hip_bfloat16* w1frag = (__hip_bfloat16*)w1fragf;
    __hip_bfloat16* w2frag = (__hip_bfloat16*)w2fragf;
    __hip_bfloat16* fc2frag= (__hip_bfloat16*)fc2fragf;
    __hip_bfloat16* hmid   = (__hip_bfloat16*)hmidf;
    __hip_bfloat16* h2pre  = (__hip_bfloat16*)h2pref;
    __hip_bfloat16* h2bf   = (__hip_bfloat16*)h2bff;
    __hip_bfloat16* h1bf   = (__hip_bfloat16*)h1bff;
    __hip_bfloat16* zsd    = (__hip_bfloat16*)zsdf;

    hipMemsetAsync(counts, 0, sizeof(int) * (size_t)N, stream);

    prep_kernel<<<64, 256, 0, stream>>>(cls, fc0_w, fc0_b, W1, W2, fc2_w, c1, w1frag, w2frag, fc2frag);
    count_kernel<<<(E + 255) / 256, 256, 0, stream>>>(dst, counts, E);
    bsum_kernel<<<nb, 256, 0, stream>>>(counts, bsum, N);
    top_scan_kernel<<<1, 64, 0, stream>>>(bsum, boff, nb);
    local_scan_kernel<<<nb, 1024, 0, stream>>>(counts, boff, rowp, woff, N, E);
    scatter_kernel<<<(E + 255) / 256, 256, 0, stream>>>(src, dst, woff, srcs, E);
    gemm1_mfma_kernel<<<(N + 63) / 64, 256, 0, stream>>>(x, w1frag, c1, att_s1, att_d1, h1bf, a_s1, a_d1, N);
    agg1_csr_kernel<<<(N + 3) / 4, 256, 0, stream>>>(rowp, srcs, a_s1, a_d1, (const unsigned*)h1bf, bias1, (unsigned*)hmid, N);
    gemm2_mfma_kernel<<<(N + 63) / 64, 256, 0, stream>>>(hmid, w2frag, att_s2, att_d2, h2pre, a_s2, a_d2, N);
    agg2_csr_kernel<<<(N + 3) / 4, 256, 0, stream>>>(rowp, srcs, a_s2, a_d2, (const unsigned*)h2pre, bias2, (unsigned*)h2bf, N);
    zsd_mfma_kernel<<<(N + 63) / 64, 256, 0, stream>>>(h2bf, fc2frag, fc2_b, zsd, N);
    edge_zsd_kernel<<<(E + 63) / 64, 256, 0, stream>>>(src, dst, (const unsigned*)zsd, fc3_w, fc3_b, out, E);
}

// Round 9
// 336.260 us; speedup vs baseline: 1.2089x; 1.0735x over previous
//
#include <hip/hip_runtime.h>
#include <hip/hip_bf16.h>
#include <math.h>

// N=50000, E=500000, SED=128, HID=64, H=2, F_node=128
// Round 9: sub-wave group-per-dst aggregation (16 lanes/dst agg1, 32 agg2;
// no shfl broadcasts, no wave reductions, unroll-2 pipelined gathers);
// count fused into gemm1; edge head with batched gathers.

typedef short short8 __attribute__((ext_vector_type(8)));
typedef float floatx4 __attribute__((ext_vector_type(4)));
typedef float v2f __attribute__((ext_vector_type(2)));
typedef unsigned uint2v __attribute__((ext_vector_type(2)));

__device__ __forceinline__ v2f bfpair(unsigned v) {
    uint2v t; t.x = v << 16; t.y = v & 0xFFFF0000u;
    return __builtin_bit_cast(v2f, t);
}
__device__ __forceinline__ unsigned short bfbits(float f) {
    return __builtin_bit_cast(unsigned short, __float2bfloat16(f));
}
__device__ __forceinline__ unsigned packbf(float a, float b) {
    return ((unsigned)bfbits(b) << 16) | (unsigned)bfbits(a);
}
__device__ __forceinline__ float lrelu(float v) { return v > 0.f ? v : 0.2f * v; }

// ---- prep: sent/c1; bf16 B-fragment tables for W1, W2, fc2(split) ----
__global__ void prep_kernel(const float* __restrict__ cls, const float* __restrict__ fc0_w,
                            const float* __restrict__ fc0_b, const float* __restrict__ W1,
                            const float* __restrict__ W2, const float* __restrict__ fc2_w,
                            float* __restrict__ c1,
                            __hip_bfloat16* __restrict__ w1frag,
                            __hip_bfloat16* __restrict__ w2frag,
                            __hip_bfloat16* __restrict__ fc2frag) {
    int tid = threadIdx.x;
    if (blockIdx.x == 0) {
        __shared__ float s_sent[128];
        if (tid < 128) {
            float acc = fc0_b[tid];
            const float* row = fc0_w + (size_t)tid * 768;
            for (int k = 0; k < 768; ++k) acc += row[k] * cls[k];
            s_sent[tid] = acc;
        }
        __syncthreads();
        if (tid < 128) {
            float acc = 0.f;
            for (int k = 0; k < 128; ++k) acc += s_sent[k] * W1[(128 + k) * 128 + tid];
            c1[tid] = acc;
        }
    }
    int gstride = gridDim.x * blockDim.x;
    int g = blockIdx.x * blockDim.x + tid;
    for (int i = g; i < 16384; i += gstride) {
        int j = i & 7, l = (i >> 3) & 63, nt = (i >> 9) & 7, kt = (i >> 12) & 3;
        int k = kt * 32 + (l >> 4) * 8 + j;
        int n = nt * 16 + (l & 15);
        w1frag[i] = __float2bfloat16(W1[k * 128 + n]);
    }
    for (int i = g; i < 32768; i += gstride) {
        int j = i & 7, l = (i >> 3) & 63, nt = (i >> 9) & 15, kt = (i >> 13) & 3;
        int k = kt * 32 + (l >> 4) * 8 + j;
        int n = nt * 16 + (l & 15);
        w2frag[i] = __float2bfloat16(W2[k * 256 + n]);
    }
    for (int i = g; i < 32768; i += gstride) {
        int j = i & 7, l = (i >> 3) & 63, nt = (i >> 9) & 15, kt = (i >> 13) & 3;
        int k = kt * 32 + (l >> 4) * 8 + j;
        int n = nt * 16 + (l & 15);
        float v = (n < 128) ? fc2_w[n * 256 + k] : fc2_w[(n - 128) * 256 + 128 + k];
        fc2frag[i] = __float2bfloat16(v);
    }
}

// ---- CSR scan (hierarchical) ----
__global__ void __launch_bounds__(256) bsum_kernel(const int* __restrict__ counts,
                                                   int* __restrict__ bsum, int N) {
    int base = blockIdx.x * 1024;
    int tid = threadIdx.x;
    int v = 0;
    #pragma unroll
    for (int k = 0; k < 4; ++k) {
        int idx = base + k * 256 + tid;
        if (idx < N) v += counts[idx];
    }
    #pragma unroll
    for (int off = 1; off < 64; off <<= 1) v += __shfl_xor(v, off, 64);
    __shared__ int ws[4];
    if ((tid & 63) == 0) ws[tid >> 6] = v;
    __syncthreads();
    if (tid == 0) bsum[blockIdx.x] = ws[0] + ws[1] + ws[2] + ws[3];
}

__global__ void top_scan_kernel(const int* __restrict__ bsum, int* __restrict__ boff, int nb) {
    int lane = threadIdx.x;
    int v = (lane < nb) ? bsum[lane] : 0;
    int x = v;
    #pragma unroll
    for (int off = 1; off < 64; off <<= 1) {
        int t = __shfl_up(x, off, 64);
        if (lane >= off) x += t;
    }
    if (lane < nb) boff[lane] = x - v;
}

__global__ void __launch_bounds__(1024) local_scan_kernel(const int* __restrict__ counts,
                                                          const int* __restrict__ boff,
                                                          int* __restrict__ row, int* __restrict__ woff,
                                                          int N, int E) {
    int tid = threadIdx.x, lane = tid & 63, wv = tid >> 6;
    int base = blockIdx.x * 1024;
    __shared__ int wsum[16];
    int v = (base + tid < N) ? counts[base + tid] : 0;
    int x = v;
    #pragma unroll
    for (int off = 1; off < 64; off <<= 1) {
        int t = __shfl_up(x, off, 64);
        if (lane >= off) x += t;
    }
    if (lane == 63) wsum[wv] = x;
    __syncthreads();
    if (wv == 0 && lane < 16) {
        int y = wsum[lane];
        #pragma unroll
        for (int off = 1; off < 16; off <<= 1) {
            int t = __shfl_up(y, off, 64);
            if (lane >= off) y += t;
        }
        wsum[lane] = y;
    }
    __syncthreads();
    int excl = boff[blockIdx.x] + (wv ? wsum[wv - 1] : 0) + x - v;
    if (base + tid < N) { row[base + tid] = excl; woff[base + tid] = excl; }
    if (blockIdx.x == 0 && tid == 0) row[N] = E;
}

__global__ void scatter_kernel(const int* __restrict__ src, const int* __restrict__ dst,
                               int* __restrict__ woff, int* __restrict__ srcs, int E) {
    int e = blockIdx.x * blockDim.x + threadIdx.x;
    if (e < E) {
        int pos = atomicAdd(&woff[dst[e]], 1);
        srcs[pos] = src[e];
    }
}

// ---- gemm1 MFMA + fused degree count: blocks [0,G1) gemm1, [G1, G1+G2) count ----
__global__ void __launch_bounds__(256) gemm1_count_kernel(
        const float* __restrict__ x, const __hip_bfloat16* __restrict__ wfrag,
        const float* __restrict__ c1, const float* __restrict__ att_s, const float* __restrict__ att_d,
        __hip_bfloat16* __restrict__ h1bf, float* __restrict__ a_src, float* __restrict__ a_dst,
        const int* __restrict__ dst, int* __restrict__ counts, int E, int G1, int N) {
    if ((int)blockIdx.x >= G1) {
        int e = ((int)blockIdx.x - G1) * 256 + threadIdx.x;
        if (e < E) atomicAdd(&counts[dst[e]], 1);
        return;
    }
    int lane = threadIdx.x & 63, wv = threadIdx.x >> 6;
    int lo = lane & 15, quad = lane >> 4;
    int rowbase = ((int)blockIdx.x * 4 + wv) * 16;
    if (rowbase >= N) return;
    int arow = rowbase + lo; if (arow >= N) arow = N - 1;
    const float* ap = x + (size_t)arow * 128 + quad * 8;
    floatx4 acc[8];
    #pragma unroll
    for (int nt = 0; nt < 8; ++nt) acc[nt] = (floatx4){0.f, 0.f, 0.f, 0.f};
    const short8* bf = (const short8*)wfrag;
    #pragma unroll
    for (int kt = 0; kt < 4; ++kt) {
        float4 fa = *(const float4*)(ap + kt * 32);
        float4 fb = *(const float4*)(ap + kt * 32 + 4);
        short8 a;
        a[0] = (short)bfbits(fa.x); a[1] = (short)bfbits(fa.y);
        a[2] = (short)bfbits(fa.z); a[3] = (short)bfbits(fa.w);
        a[4] = (short)bfbits(fb.x); a[5] = (short)bfbits(fb.y);
        a[6] = (short)bfbits(fb.z); a[7] = (short)bfbits(fb.w);
        #pragma unroll
        for (int nt = 0; nt < 8; ++nt)
            acc[nt] = __builtin_amdgcn_mfma_f32_16x16x32_bf16(a, bf[(kt * 8 + nt) * 64 + lane], acc[nt], 0, 0, 0);
    }
    float ps0[4] = {0,0,0,0}, ps1[4] = {0,0,0,0}, pd0[4] = {0,0,0,0}, pd1[4] = {0,0,0,0};
    #pragma unroll
    for (int nt = 0; nt < 8; ++nt) {
        int ch = nt * 16 + lo;
        float cv = c1[ch], as_v = att_s[ch], ad_v = att_d[ch];
        #pragma unroll
        for (int r = 0; r < 4; ++r) {
            int row = rowbase + quad * 4 + r;
            float val = acc[nt][r] + cv;
            if (row < N) ((unsigned short*)h1bf)[(size_t)row * 128 + ch] = bfbits(val);
            if (nt < 4) { ps0[r] += val * as_v; pd0[r] += val * ad_v; }
            else        { ps1[r] += val * as_v; pd1[r] += val * ad_v; }
        }
    }
    #pragma unroll
    for (int r = 0; r < 4; ++r) {
        int row = rowbase + quad * 4 + r;
        float v0 = ps0[r], v1 = ps1[r], v2 = pd0[r], v3 = pd1[r];
        #pragma unroll
        for (int off = 1; off < 16; off <<= 1) {
            v0 += __shfl_xor(v0, off, 64); v1 += __shfl_xor(v1, off, 64);
            v2 += __shfl_xor(v2, off, 64); v3 += __shfl_xor(v3, off, 64);
        }
        if (lo == 0 && row < N) {
            a_src[row * 2 + 0] = v0; a_src[row * 2 + 1] = v1;
            a_dst[row * 2 + 0] = v2; a_dst[row * 2 + 1] = v3;
        }
    }
}

// ---- agg1: 16 lanes per dst (4 dst/wave); no cross-lane ops; ELU -> hmid bf16 ----
__global__ void __launch_bounds__(256) agg1_csr_kernel(
        const int* __restrict__ row, const int* __restrict__ srcs,
        const float* __restrict__ a_src, const float* __restrict__ a_dst,
        const unsigned* __restrict__ h1u, const float* __restrict__ bias1,
        unsigned* __restrict__ hmid_u, int N) {
    int tid = threadIdx.x;
    int d = blockIdx.x * 16 + (tid >> 4);
    if (d >= N) return;
    int q = tid & 15;
    int beg = row[d], end = row[d + 1];
    float2 adp = ((const float2*)a_dst)[d];
    float den0 = 0.f, den1 = 0.f;
    v2f facc2[4];
    #pragma unroll
    for (int m = 0; m < 4; ++m) facc2[m] = (v2f){0.f, 0.f};
    for (int i = beg; i < end; i += 2) {
        int s0 = srcs[i];
        bool has1 = (i + 1) < end;
        int s1 = has1 ? srcs[i + 1] : s0;
        float2 as0 = ((const float2*)a_src)[s0];
        float2 as1 = ((const float2*)a_src)[s1];
        uint4 u0 = ((const uint4*)(h1u + (size_t)s0 * 64))[q];
        uint4 u1 = ((const uint4*)(h1u + (size_t)s1 * 64))[q];
        float e00 = __expf(lrelu(as0.x + adp.x));
        float e01 = __expf(lrelu(as0.y + adp.y));
        float e10 = has1 ? __expf(lrelu(as1.x + adp.x)) : 0.f;
        float e11 = has1 ? __expf(lrelu(as1.y + adp.y)) : 0.f;
        den0 += e00 + e10;
        den1 += e01 + e11;
        float w0 = (q < 8) ? e00 : e01;
        float w1 = (q < 8) ? e10 : e11;
        facc2[0] += bfpair(u0.x) * w0 + bfpair(u1.x) * w1;
        facc2[1] += bfpair(u0.y) * w0 + bfpair(u1.y) * w1;
        facc2[2] += bfpair(u0.z) * w0 + bfpair(u1.z) * w1;
        facc2[3] += bfpair(u0.w) * w0 + bfpair(u1.w) * w1;
    }
    float inv = 1.f / (((q < 8) ? den0 : den1) + 1e-16f);
    int c0 = 8 * q;
    float v[8];
    #pragma unroll
    for (int m = 0; m < 4; ++m) {
        float va = facc2[m].x * inv + bias1[c0 + 2 * m];
        float vb = facc2[m].y * inv + bias1[c0 + 2 * m + 1];
        v[2 * m]     = va > 0.f ? va : expm1f(va);
        v[2 * m + 1] = vb > 0.f ? vb : expm1f(vb);
    }
    uint4 o;
    o.x = packbf(v[0], v[1]); o.y = packbf(v[2], v[3]);
    o.z = packbf(v[4], v[5]); o.w = packbf(v[6], v[7]);
    ((uint4*)(hmid_u + (size_t)d * 64))[q] = o;
}

// ---- gemm2 MFMA: h2pre[N,256](bf16) = hmid @ W2frag ; logits ----
__global__ void __launch_bounds__(256) gemm2_mfma_kernel(
        const __hip_bfloat16* __restrict__ hmid, const __hip_bfloat16* __restrict__ wfrag,
        const float* __restrict__ att_s, const float* __restrict__ att_d,
        __hip_bfloat16* __restrict__ h2pre, float* __restrict__ a_src, float* __restrict__ a_dst, int N) {
    int lane = threadIdx.x & 63, wv = threadIdx.x >> 6;
    int lo = lane & 15, quad = lane >> 4;
    int rowbase = (blockIdx.x * 4 + wv) * 16;
    if (rowbase >= N) return;
    int arow = rowbase + lo; if (arow >= N) arow = N - 1;
    const __hip_bfloat16* ap = hmid + (size_t)arow * 128 + quad * 8;
    floatx4 acc[16];
    #pragma unroll
    for (int nt = 0; nt < 16; ++nt) acc[nt] = (floatx4){0.f, 0.f, 0.f, 0.f};
    const short8* bf = (const short8*)wfrag;
    #pragma unroll
    for (int kt = 0; kt < 4; ++kt) {
        short8 a = *(const short8*)(ap + kt * 32);
        #pragma unroll
        for (int nt = 0; nt < 16; ++nt)
            acc[nt] = __builtin_amdgcn_mfma_f32_16x16x32_bf16(a, bf[(kt * 16 + nt) * 64 + lane], acc[nt], 0, 0, 0);
    }
    float ps0[4] = {0,0,0,0}, ps1[4] = {0,0,0,0}, pd0[4] = {0,0,0,0}, pd1[4] = {0,0,0,0};
    #pragma unroll
    for (int nt = 0; nt < 16; ++nt) {
        int ch = nt * 16 + lo;
        float as_v = att_s[ch], ad_v = att_d[ch];
        #pragma unroll
        for (int r = 0; r < 4; ++r) {
            int row = rowbase + quad * 4 + r;
            float val = acc[nt][r];
            if (row < N) ((unsigned short*)h2pre)[(size_t)row * 256 + ch] = bfbits(val);
            if (nt < 8) { ps0[r] += val * as_v; pd0[r] += val * ad_v; }
            else        { ps1[r] += val * as_v; pd1[r] += val * ad_v; }
        }
    }
    #pragma unroll
    for (int r = 0; r < 4; ++r) {
        int row = rowbase + quad * 4 + r;
        float v0 = ps0[r], v1 = ps1[r], v2 = pd0[r], v3 = pd1[r];
        #pragma unroll
        for (int off = 1; off < 16; off <<= 1) {
            v0 += __shfl_xor(v0, off, 64); v1 += __shfl_xor(v1, off, 64);
            v2 += __shfl_xor(v2, off, 64); v3 += __shfl_xor(v3, off, 64);
        }
        if (lo == 0 && row < N) {
            a_src[row * 2 + 0] = v0; a_src[row * 2 + 1] = v1;
            a_dst[row * 2 + 0] = v2; a_dst[row * 2 + 1] = v3;
        }
    }
}

// ---- agg2: 32 lanes per dst (2 dst/wave); head-mean via one shfl_xor(16) ----
__global__ void __launch_bounds__(256) agg2_csr_kernel(
        const int* __restrict__ row, const int* __restrict__ srcs,
        const float* __restrict__ a_src, const float* __restrict__ a_dst,
        const unsigned* __restrict__ h2u, const float* __restrict__ bias2,
        unsigned* __restrict__ h2bf_u, int N) {
    int tid = threadIdx.x;
    int d = blockIdx.x * 8 + (tid >> 5);
    if (d >= N) return;
    int q = tid & 31;
    int beg = row[d], end = row[d + 1];
    float2 adp = ((const float2*)a_dst)[d];
    float den0 = 0.f, den1 = 0.f;
    v2f facc2[4];
    #pragma unroll
    for (int m = 0; m < 4; ++m) facc2[m] = (v2f){0.f, 0.f};
    for (int i = beg; i < end; i += 2) {
        int s0 = srcs[i];
        bool has1 = (i + 1) < end;
        int s1 = has1 ? srcs[i + 1] : s0;
        float2 as0 = ((const float2*)a_src)[s0];
        float2 as1 = ((const float2*)a_src)[s1];
        uint4 u0 = ((const uint4*)(h2u + (size_t)s0 * 128))[q];
        uint4 u1 = ((const uint4*)(h2u + (size_t)s1 * 128))[q];
        float e00 = __expf(lrelu(as0.x + adp.x));
        float e01 = __expf(lrelu(as0.y + adp.y));
        float e10 = has1 ? __expf(lrelu(as1.x + adp.x)) : 0.f;
        float e11 = has1 ? __expf(lrelu(as1.y + adp.y)) : 0.f;
        den0 += e00 + e10;
        den1 += e01 + e11;
        float w0 = (q < 16) ? e00 : e01;
        float w1 = (q < 16) ? e10 : e11;
        facc2[0] += bfpair(u0.x) * w0 + bfpair(u1.x) * w1;
        facc2[1] += bfpair(u0.y) * w0 + bfpair(u1.y) * w1;
        facc2[2] += bfpair(u0.z) * w0 + bfpair(u1.z) * w1;
        facc2[3] += bfpair(u0.w) * w0 + bfpair(u1.w) * w1;
    }
    float inv = 0.5f / (((q < 16) ? den0 : den1) + 1e-16f);
    #pragma unroll
    for (int m = 0; m < 4; ++m) {
        facc2[m] *= inv;
        facc2[m].x += __shfl_xor(facc2[m].x, 16, 64);  // combine heads
        facc2[m].y += __shfl_xor(facc2[m].y, 16, 64);
    }
    if (q < 16) {
        int c0 = 8 * q;
        uint4 o;
        o.x = packbf(facc2[0].x + bias2[c0 + 0], facc2[0].y + bias2[c0 + 1]);
        o.y = packbf(facc2[1].x + bias2[c0 + 2], facc2[1].y + bias2[c0 + 3]);
        o.z = packbf(facc2[2].x + bias2[c0 + 4], facc2[2].y + bias2[c0 + 5]);
        o.w = packbf(facc2[3].x + bias2[c0 + 6], facc2[3].y + bias2[c0 + 7]);
        ((uint4*)(h2bf_u + (size_t)d * 64))[q] = o;
    }
}

// ---- zsd MFMA: zsd[N,256](bf16): [zs | zd + fc2_b] = h2bf @ fc2frag ----
__global__ void __launch_bounds__(256) zsd_mfma_kernel(
        const __hip_bfloat16* __restrict__ h2bf, const __hip_bfloat16* __restrict__ wfrag,
        const float* __restrict__ fc2_b, __hip_bfloat16* __restrict__ zsd, int N) {
    int lane = threadIdx.x & 63, wv = threadIdx.x >> 6;
    int lo = lane & 15, quad = lane >> 4;
    int rowbase = (blockIdx.x * 4 + wv) * 16;
    if (rowbase >= N) return;
    int arow = rowbase + lo; if (arow >= N) arow = N - 1;
    const __hip_bfloat16* ap = h2bf + (size_t)arow * 128 + quad * 8;
    floatx4 acc[16];
    #pragma unroll
    for (int nt = 0; nt < 16; ++nt) acc[nt] = (floatx4){0.f, 0.f, 0.f, 0.f};
    const short8* bf = (const short8*)wfrag;
    #pragma unroll
    for (int kt = 0; kt < 4; ++kt) {
        short8 a = *(const short8*)(ap + kt * 32);
        #pragma unroll
        for (int nt = 0; nt < 16; ++nt)
            acc[nt] = __builtin_amdgcn_mfma_f32_16x16x32_bf16(a, bf[(kt * 16 + nt) * 64 + lane], acc[nt], 0, 0, 0);
    }
    #pragma unroll
    for (int nt = 0; nt < 16; ++nt) {
        int ch = nt * 16 + lo;
        float bv = (nt >= 8) ? fc2_b[ch - 128] : 0.f;
        #pragma unroll
        for (int r = 0; r < 4; ++r) {
            int row = rowbase + quad * 4 + r;
            if (row < N) ((unsigned short*)zsd)[(size_t)row * 256 + ch] = bfbits(acc[nt][r] + bv);
        }
    }
}

// ---- edge head: batched gathers (8 rounds), channel-split, shfl_xor(16) add ----
__global__ void __launch_bounds__(256) edge_zsd_kernel(
        const int* __restrict__ src, const int* __restrict__ dst,
        const unsigned* __restrict__ zsd_u, const float* __restrict__ fc3_w,
        const float* __restrict__ fc3_b, float* __restrict__ out, int E) {
    int lane = threadIdx.x & 63, wv = threadIdx.x >> 6;
    int g = lane >> 5, r = (lane >> 4) & 1, q = lane & 15;
    int base = (blockIdx.x * 4 + wv) * 16;
    if (base >= E) return;
    v2f f30 = {fc3_w[8 * q + 4 * r + 0], fc3_w[8 * q + 4 * r + 1]};
    v2f f31 = {fc3_w[8 * q + 4 * r + 2], fc3_w[8 * q + 4 * r + 3]};
    float b3 = fc3_b[0];
    int nodes[8];
    #pragma unroll
    for (int j = 0; j < 8; ++j) {
        int e = base + 2 * j + g;
        int ec = e < E ? e : E - 1;
        nodes[j] = r ? dst[ec] : src[ec];
    }
    uint4 rows[8];
    #pragma unroll
    for (int j = 0; j < 8; ++j)
        rows[j] = ((const uint4*)(zsd_u + (size_t)nodes[j] * 128 + (r << 6)))[q];
    #pragma unroll
    for (int j = 0; j < 8; ++j) {
        uint4 mine = rows[j];
        unsigned sx = (unsigned)__shfl_xor((int)mine.x, 16, 64);
        unsigned sy = (unsigned)__shfl_xor((int)mine.y, 16, 64);
        unsigned sz = (unsigned)__shfl_xor((int)mine.z, 16, 64);
        unsigned sw = (unsigned)__shfl_xor((int)mine.w, 16, 64);
        unsigned mA = r ? mine.z : mine.x;
        unsigned mB = r ? mine.w : mine.y;
        unsigned oA = r ? sz : sx;
        unsigned oB = r ? sw : sy;
        v2f sA = bfpair(mA) + bfpair(oA);
        v2f sB = bfpair(mB) + bfpair(oB);
        sA.x = fmaxf(sA.x, 0.f); sA.y = fmaxf(sA.y, 0.f);
        sB.x = fmaxf(sB.x, 0.f); sB.y = fmaxf(sB.y, 0.f);
        v2f p2 = sA * f30 + sB * f31;
        float p = p2.x + p2.y;
        #pragma unroll
        for (int off = 1; off < 32; off <<= 1) p += __shfl_xor(p, off, 64);
        int e = base + 2 * j + g;
        if ((lane & 31) == 0 && e < E)
            out[e] = 1.f / (1.f + expf(-(p + b3)));
    }
}

extern "C" void kernel_launch(void* const* d_in, const int* in_sizes, int n_in,
                              void* d_out, int out_size, void* d_ws, size_t ws_size,
                              hipStream_t stream) {
    const float* x      = (const float*)d_in[0];
    const int*   ei     = (const int*)d_in[1];
    const float* cls    = (const float*)d_in[2];
    const float* fc0_w  = (const float*)d_in[3];
    const float* fc0_b  = (const float*)d_in[4];
    const float* W1     = (const float*)d_in[5];
    const float* att_s1 = (const float*)d_in[6];
    const float* att_d1 = (const float*)d_in[7];
    const float* bias1  = (const float*)d_in[8];
    const float* W2     = (const float*)d_in[9];
    const float* att_s2 = (const float*)d_in[10];
    const float* att_d2 = (const float*)d_in[11];
    const float* bias2  = (const float*)d_in[12];
    const float* fc2_w  = (const float*)d_in[13];
    const float* fc2_b  = (const float*)d_in[14];
    const float* fc3_w  = (const float*)d_in[15];
    const float* fc3_b  = (const float*)d_in[16];
    float* out = (float*)d_out;

    int N = in_sizes[0] / 128;
    int E = in_sizes[1] / 2;
    const int* src = ei;
    const int* dst = ei + E;
    int nb = (N + 1023) / 1024;

    float* w = (float*)d_ws;
    size_t off = 0;
    auto alloc = [&](size_t n) { float* p = w + off; off += (n + 63) & ~(size_t)63; return p; };
    float* c1      = alloc(128);
    float* w1fragf = alloc(16384 / 2);
    float* w2fragf = alloc(32768 / 2);
    float* fc2fragf= alloc(32768 / 2);
    float* a_s1    = alloc((size_t)N * 2);
    float* a_d1    = alloc((size_t)N * 2);
    float* a_s2    = alloc((size_t)N * 2);
    float* a_d2    = alloc((size_t)N * 2);
    float* h1bff   = alloc((size_t)N * 64);   // N*128 bf16
    float* hmidf   = alloc((size_t)N * 64);   // N*128 bf16
    float* h2pref  = alloc((size_t)N * 128);  // N*256 bf16
    float* h2bff   = alloc((size_t)N * 64);   // N*128 bf16
    float* zsdf    = alloc((size_t)N * 128);  // N*256 bf16
    int* counts = (int*)alloc(N);
    int* rowp   = (int*)alloc(N + 1);
    int* woff   = (int*)alloc(N);
    int* srcs   = (int*)alloc(E);
    int* bsum   = (int*)alloc(64);
    int* boff   = (int*)alloc(64);
    __hip_bfloat16* w1frag = (__hip_bfloat16*)w1fragf;
    __hip_bfloat16* w2frag = (__hip_bfloat16*)w2fragf;
    __hip_bfloat16* fc2frag= (__hip_bfloat16*)fc2fragf;
    __hip_bfloat16* hmid   = (__hip_bfloat16*)hmidf;
    __hip_bfloat16* h2pre  = (__hip_bfloat16*)h2pref;
    __hip_bfloat16* h2bf   = (__hip_bfloat16*)h2bff;
    __hip_bfloat16* h1bf   = (__hip_bfloat16*)h1bff;
    __hip_bfloat16* zsd    = (__hip_bfloat16*)zsdf;

    hipMemsetAsync(counts, 0, sizeof(int) * (size_t)N, stream);

    prep_kernel<<<64, 256, 0, stream>>>(cls, fc0_w, fc0_b, W1, W2, fc2_w, c1, w1frag, w2frag, fc2frag);
    int G1 = (N + 63) / 64;
    int G2 = (E + 255) / 256;
    gemm1_count_kernel<<<G1 + G2, 256, 0, stream>>>(x, w1frag, c1, att_s1, att_d1, h1bf, a_s1, a_d1,
                                                    dst, counts, E, G1, N);
    bsum_kernel<<<nb, 256, 0, stream>>>(counts, bsum, N);
    top_scan_kernel<<<1, 64, 0, stream>>>(bsum, boff, nb);
    local_scan_kernel<<<nb, 1024, 0, stream>>>(counts, boff, rowp, woff, N, E);
    scatter_kernel<<<(E + 255) / 256, 256, 0, stream>>>(src, dst, woff, srcs, E);
    agg1_csr_kernel<<<(N + 15) / 16, 256, 0, stream>>>(rowp, srcs, a_s1, a_d1, (const unsigned*)h1bf, bias1, (unsigned*)hmid, N);
    gemm2_mfma_kernel<<<(N + 63) / 64, 256, 0, stream>>>(hmid, w2frag, att_s2, att_d2, h2pre, a_s2, a_d2, N);
    agg2_csr_kernel<<<(N + 7) / 8, 256, 0, stream>>>(rowp, srcs, a_s2, a_d2, (const unsigned*)h2pre, bias2, (unsigned*)h2bf, N);
    zsd_mfma_kernel<<<(N + 63) / 64, 256, 0, stream>>>(h2bf, fc2frag, fc2_b, zsd, N);
    edge_zsd_kernel<<<(E + 63) / 64, 256, 0, stream>>>(src, dst, (const unsigned*)zsd, fc3_w, fc3_b, out, E);
}